// Round 3
// baseline (321.691 us; speedup 1.0000x reference)
//
#include <hip/hip_runtime.h>
#include <math.h>

#define N_NODES   50000
#define N_EDGES   400000
#define NCH       16
#define RCUT      10.0f

// ---------------- K1: per-edge geometry + src histogram ----------------
__global__ void geom_hist_kernel(const float* __restrict__ pos,
                                 const int* __restrict__ src,
                                 const int* __restrict__ dst,
                                 float* __restrict__ dists,
                                 float* __restrict__ unit,
                                 int* __restrict__ cnt) {
    int e = blockIdx.x * blockDim.x + threadIdx.x;
    if (e >= N_EDGES) return;
    int s = src[e];
    int d = dst[e];
    float rx = pos[3 * s + 0] - pos[3 * d + 0];
    float ry = pos[3 * s + 1] - pos[3 * d + 1];
    float rz = pos[3 * s + 2] - pos[3 * d + 2];
    float dist = sqrtf(rx * rx + ry * ry + rz * rz);
    dists[e] = dist;
    float inv = 1.0f / dist;
    unit[3 * e + 0] = rx * inv;
    unit[3 * e + 1] = ry * inv;
    unit[3 * e + 2] = rz * inv;
    atomicAdd(&cnt[s], 1);
}

// ---------------- K2: single-block scan over cnt -> offsets, cursor ----------------
__global__ void scan_kernel(const int* __restrict__ cnt,
                            int* __restrict__ offsets,
                            int* __restrict__ cursor) {
    __shared__ int part[1024];
    int t = threadIdx.x;
    const int CH = (N_NODES + 1023) / 1024;  // 49
    int beg = t * CH;
    int end = beg + CH;
    if (end > N_NODES) end = N_NODES;
    int sum = 0;
    for (int i = beg; i < end; ++i) sum += cnt[i];
    part[t] = sum;
    __syncthreads();
    for (int s = 1; s < 1024; s <<= 1) {
        int x = 0;
        if (t >= s) x = part[t - s];
        __syncthreads();
        if (t >= s) part[t] += x;
        __syncthreads();
    }
    int run = (t > 0) ? part[t - 1] : 0;  // exclusive base for this chunk
    for (int i = beg; i < end; ++i) {
        offsets[i] = run;
        cursor[i] = run;
        run += cnt[i];
    }
    if (t == 0) offsets[N_NODES] = N_EDGES;
}

// ---------------- K3: fill CSR + slot-ordered packed edge data ----------------
// edata[slot] = {ux, uy, uz, bits(dst)} -> main kernel reads it coalesced.
__global__ void fill_csr_kernel(const int* __restrict__ src,
                                const int* __restrict__ dst,
                                const float* __restrict__ unit,
                                int* __restrict__ cursor,
                                int* __restrict__ csr,
                                float4* __restrict__ edata) {
    int e = blockIdx.x * blockDim.x + threadIdx.x;
    if (e >= N_EDGES) return;
    int slot = atomicAdd(&cursor[src[e]], 1);
    csr[slot] = e;
    float4 ed;
    ed.x = unit[3 * e + 0];
    ed.y = unit[3 * e + 1];
    ed.z = unit[3 * e + 2];
    ed.w = __int_as_float(dst[e]);
    edata[slot] = ed;
}

// ---------------- K4: main, one thread per (node, channel) ----------------
__global__ void node_gather_kernel(const float* __restrict__ h0,
                                   const float* __restrict__ h1,
                                   const float* __restrict__ h2,
                                   const float* __restrict__ dists,
                                   const int* __restrict__ offsets,
                                   const int* __restrict__ csr,
                                   const float4* __restrict__ edata,
                                   float* __restrict__ out0,
                                   float* __restrict__ out1,
                                   float* __restrict__ out2) {
    int t = blockIdx.x * blockDim.x + threadIdx.x;
    if (t >= N_NODES * NCH) return;
    int n = t >> 4;
    int k = t & 15;
    int beg = offsets[n];
    int end = offsets[n + 1];

    float acc0 = 0.0f;
    float acc1[3] = {0.0f, 0.0f, 0.0f};
    float acc2[9] = {0.0f, 0.0f, 0.0f, 0.0f, 0.0f, 0.0f, 0.0f, 0.0f, 0.0f};

#define PROCESS_EDGE(IDX)                                                         \
    {                                                                             \
        float4 ed = edata[IDX];                                                   \
        int e = csr[IDX];                                                         \
        int d = __float_as_int(ed.w);                                             \
        int f = e * NCH + k;                                                      \
        int n_idx = f / N_EDGES;                                                  \
        int e_idx = f - n_idx * N_EDGES;                                          \
        float r = dists[e_idx];                                                   \
        float R = 0.44721359549995794f *                                          \
                  sinf((float)(n_idx + 1) * 0.3141592653589793f * r) / r;         \
        float ux = ed.x, uy = ed.y, uz = ed.z;                                    \
        float u[3] = {ux, uy, uz};                                                \
        float A0 = h0[d * NCH + k];                                               \
        const float* a1p = h1 + ((size_t)d * NCH + k) * 3;                        \
        float A1[3] = {a1p[0], a1p[1], a1p[2]};                                   \
        const float* a2p = h2 + ((size_t)d * NCH + k) * 9;                        \
        float A2[9];                                                              \
        _Pragma("unroll") for (int j = 0; j < 9; ++j) A2[j] = a2p[j];             \
        float d1 = A1[0] * ux + A1[1] * uy + A1[2] * uz;                          \
        float tA = A2[0] + A2[4] + A2[8];                                         \
        float v0 = A2[0] * ux + A2[1] * uy + A2[2] * uz;                          \
        float v1 = A2[3] * ux + A2[4] * uy + A2[5] * uz;                          \
        float v2 = A2[6] * ux + A2[7] * uy + A2[8] * uz;                          \
        float w0 = A2[0] * ux + A2[3] * uy + A2[6] * uz;                          \
        float w1 = A2[1] * ux + A2[4] * uy + A2[7] * uz;                          \
        float w2 = A2[2] * ux + A2[5] * uy + A2[8] * uz;                          \
        float q = ux * v0 + uy * v1 + uz * v2;                                    \
        acc0 += R * (2.0f * A0 + d1 + 2.0f * tA + 2.0f * q);                      \
        float svw[3] = {v0 + w0, v1 + w1, v2 + w2};                               \
        float a0t = A0 + tA;                                                      \
        _Pragma("unroll") for (int m = 0; m < 3; ++m) {                           \
            acc1[m] += R * (A0 * u[m] + 2.0f * A1[m] + 2.0f * d1 * u[m] +         \
                            svw[m] + tA * u[m]);                                  \
            _Pragma("unroll") for (int nn = 0; nn < 3; ++nn) {                    \
                acc2[3 * m + nn] += R * (a0t * u[m] * u[nn] + A1[m] * u[nn] +     \
                                         2.0f * A2[3 * m + nn] +                  \
                                         2.0f * svw[m] * u[nn]);                  \
            }                                                                     \
        }                                                                         \
    }

    int i = beg;
    for (; i + 1 < end; i += 2) {
        PROCESS_EDGE(i);
        PROCESS_EDGE(i + 1);
    }
    if (i < end) {
        PROCESS_EDGE(i);
    }
#undef PROCESS_EDGE

    out0[t] = acc0;
    float* o1p = out1 + (size_t)t * 3;
#pragma unroll
    for (int m = 0; m < 3; ++m) o1p[m] = acc1[m];
    float* o2p = out2 + (size_t)t * 9;
#pragma unroll
    for (int m = 0; m < 9; ++m) o2p[m] = acc2[m];
}

extern "C" void kernel_launch(void* const* d_in, const int* in_sizes, int n_in,
                              void* d_out, int out_size, void* d_ws, size_t ws_size,
                              hipStream_t stream) {
    const float* h0  = (const float*)d_in[0];
    const float* h1  = (const float*)d_in[1];
    const float* h2  = (const float*)d_in[2];
    const float* pos = (const float*)d_in[3];
    // d_in[4] = channel_weights: dead in the reference dataflow
    const int* edge_index = (const int*)d_in[5];
    const int* src = edge_index;
    const int* dst = edge_index + N_EDGES;

    float* out = (float*)d_out;
    float* out0 = out;                                  // [N,16]
    float* out1 = out + (size_t)N_NODES * NCH;          // [N,16,3]
    float* out2 = out + (size_t)N_NODES * NCH * 4;      // [N,16,9]

    // workspace layout (float4 first for 16-B alignment)
    float4* edata  = (float4*)d_ws;                     // [E]
    float* dists   = (float*)(edata + N_EDGES);         // [E]
    float* unit    = dists + N_EDGES;                   // [E,3]
    int* cnt       = (int*)(unit + (size_t)N_EDGES * 3);// [N]
    int* offsets   = cnt + N_NODES;                     // [N+1]
    int* cursor    = offsets + N_NODES + 1;             // [N]
    int* csr       = cursor + N_NODES;                  // [E]
    // total ~15.2 MB

    const int NB_EDGES = (N_EDGES + 255) / 256;

    hipMemsetAsync(cnt, 0, N_NODES * sizeof(int), stream);
    geom_hist_kernel<<<NB_EDGES, 256, 0, stream>>>(pos, src, dst, dists, unit, cnt);
    scan_kernel<<<1, 1024, 0, stream>>>(cnt, offsets, cursor);
    fill_csr_kernel<<<NB_EDGES, 256, 0, stream>>>(src, dst, unit, cursor, csr, edata);

    const int TOTAL = N_NODES * NCH;
    node_gather_kernel<<<(TOTAL + 255) / 256, 256, 0, stream>>>(
        h0, h1, h2, dists, offsets, csr, edata, out0, out1, out2);
}

// Round 4
// 211.183 us; speedup vs baseline: 1.5233x; 1.5233x over previous
//
#include <hip/hip_runtime.h>
#include <math.h>

#define N_NODES   50000
#define N_EDGES   400000
#define NCH       16
#define RCUT      10.0f

// ---------------- K1: per-edge geometry + src histogram ----------------
__global__ void geom_hist_kernel(const float* __restrict__ pos,
                                 const int* __restrict__ src,
                                 const int* __restrict__ dst,
                                 float* __restrict__ dists,
                                 float* __restrict__ unit,
                                 int* __restrict__ cnt) {
    int e = blockIdx.x * blockDim.x + threadIdx.x;
    if (e >= N_EDGES) return;
    int s = src[e];
    int d = dst[e];
    float rx = pos[3 * s + 0] - pos[3 * d + 0];
    float ry = pos[3 * s + 1] - pos[3 * d + 1];
    float rz = pos[3 * s + 2] - pos[3 * d + 2];
    float dist = sqrtf(rx * rx + ry * ry + rz * rz);
    dists[e] = dist;
    float inv = 1.0f / dist;
    unit[3 * e + 0] = rx * inv;
    unit[3 * e + 1] = ry * inv;
    unit[3 * e + 2] = rz * inv;
    atomicAdd(&cnt[s], 1);
}

// ---------------- K2: per-256-block inclusive scan ----------------
__global__ void scan_blocks_kernel(const int* __restrict__ cnt,
                                   int* __restrict__ incl,
                                   int* __restrict__ bsum) {
    __shared__ int sh[256];
    int t = threadIdx.x;
    int i = blockIdx.x * 256 + t;
    int v = (i < N_NODES) ? cnt[i] : 0;
    sh[t] = v;
    __syncthreads();
    for (int s = 1; s < 256; s <<= 1) {
        int x = 0;
        if (t >= s) x = sh[t - s];
        __syncthreads();
        if (t >= s) sh[t] += x;
        __syncthreads();
    }
    if (i < N_NODES) incl[i] = sh[t];
    if (t == 255) bsum[blockIdx.x] = sh[255];
}

// ---------------- K3: finalize offsets (block base via in-block reduction) ----
__global__ void finalize_kernel(const int* __restrict__ cnt,
                                const int* __restrict__ incl,
                                const int* __restrict__ bsum,
                                int* __restrict__ offsets,
                                int* __restrict__ cursor) {
    __shared__ int sh[256];
    int t = threadIdx.x;
    int b = blockIdx.x;              // < 196
    sh[t] = (t < b) ? bsum[t] : 0;   // exclusive prefix of block sums
    __syncthreads();
    for (int s = 128; s > 0; s >>= 1) {
        if (t < s) sh[t] += sh[t + s];
        __syncthreads();
    }
    int base = sh[0];
    int i = b * 256 + t;
    if (i < N_NODES) {
        int off = incl[i] - cnt[i] + base;
        offsets[i] = off;
        cursor[i] = off;
    }
    if (b == 0 && t == 0) offsets[N_NODES] = N_EDGES;
}

// ---------------- K4: fill slot-ordered edata + radial ----------------
// edata[slot] = {ux,uy,uz,bits(dst)}; radial[slot*16+k] = RBF with the
// reference's faithful [K,E]->[E,K] reshape (uses OTHER edges' distances).
__global__ void fill_kernel(const int* __restrict__ src,
                            const int* __restrict__ dst,
                            const float* __restrict__ unit,
                            const float* __restrict__ dists,
                            int* __restrict__ cursor,
                            float4* __restrict__ edata,
                            float* __restrict__ radial) {
    int e = blockIdx.x * blockDim.x + threadIdx.x;
    if (e >= N_EDGES) return;
    int slot = atomicAdd(&cursor[src[e]], 1);
    float4 ed;
    ed.x = unit[3 * e + 0];
    ed.y = unit[3 * e + 1];
    ed.z = unit[3 * e + 2];
    ed.w = __int_as_float(dst[e]);
    edata[slot] = ed;
    float* rp = radial + (size_t)slot * NCH;
    int f0 = e * NCH;
#pragma unroll
    for (int k = 0; k < NCH; ++k) {
        int f = f0 + k;
        int n_idx = f / N_EDGES;           // magic-mul div
        int e_idx = f - n_idx * N_EDGES;
        float r = dists[e_idx];
        rp[k] = 0.44721359549995794f *
                __sinf((float)(n_idx + 1) * 0.3141592653589793f * r) / r;
    }
}

// ---------------- K5: main — one WAVE per node ----------------
// lane = j*16 + k: k = channel, j = 4-way edge split; xor-shuffle reduce over j.
__global__ void node_wave_kernel(const float* __restrict__ h0,
                                 const float* __restrict__ h1,
                                 const float* __restrict__ h2,
                                 const int* __restrict__ offsets,
                                 const float4* __restrict__ edata,
                                 const float* __restrict__ radial,
                                 float* __restrict__ out0,
                                 float* __restrict__ out1,
                                 float* __restrict__ out2) {
    int gid = blockIdx.x * blockDim.x + threadIdx.x;
    int node = gid >> 6;
    if (node >= N_NODES) return;
    int lane = threadIdx.x & 63;
    int k = lane & 15;
    int j = lane >> 4;
    int beg = offsets[node];
    int end = offsets[node + 1];

    float acc0 = 0.0f;
    float acc1[3] = {0.0f, 0.0f, 0.0f};
    float acc2[9] = {0.0f, 0.0f, 0.0f, 0.0f, 0.0f, 0.0f, 0.0f, 0.0f, 0.0f};

    for (int i = beg + j; i < end; i += 4) {
        float4 ed = edata[i];
        int d = __float_as_int(ed.w);
        float R = radial[(size_t)i * NCH + k];
        float ux = ed.x, uy = ed.y, uz = ed.z;
        float u[3] = {ux, uy, uz};

        float A0 = h0[d * NCH + k];
        const float* a1p = h1 + ((size_t)d * NCH + k) * 3;
        float A1[3] = {a1p[0], a1p[1], a1p[2]};
        const float* a2p = h2 + ((size_t)d * NCH + k) * 9;
        float A2[9];
#pragma unroll
        for (int q2 = 0; q2 < 9; ++q2) A2[q2] = a2p[q2];

        float d1 = A1[0] * ux + A1[1] * uy + A1[2] * uz;   // A1.u
        float tA = A2[0] + A2[4] + A2[8];                   // tr(A2)
        float v0 = A2[0] * ux + A2[1] * uy + A2[2] * uz;    // A2 u
        float v1 = A2[3] * ux + A2[4] * uy + A2[5] * uz;
        float v2 = A2[6] * ux + A2[7] * uy + A2[8] * uz;
        float w0 = A2[0] * ux + A2[3] * uy + A2[6] * uz;    // A2^T u
        float w1 = A2[1] * ux + A2[4] * uy + A2[7] * uz;
        float w2 = A2[2] * ux + A2[5] * uy + A2[8] * uz;
        float q = ux * v0 + uy * v1 + uz * v2;              // u^T A2 u

        acc0 += R * (2.0f * A0 + d1 + 2.0f * tA + 2.0f * q);

        float svw[3] = {v0 + w0, v1 + w1, v2 + w2};
        float a0t = A0 + tA;
#pragma unroll
        for (int m = 0; m < 3; ++m) {
            acc1[m] += R * (A0 * u[m] + 2.0f * A1[m] + 2.0f * d1 * u[m]
                            + svw[m] + tA * u[m]);
#pragma unroll
            for (int nn = 0; nn < 3; ++nn) {
                acc2[3 * m + nn] += R * (a0t * u[m] * u[nn] + A1[m] * u[nn]
                                         + 2.0f * A2[3 * m + nn]
                                         + 2.0f * svw[m] * u[nn]);
            }
        }
    }

    // reduce across j (lanes xor 16, xor 32)
    acc0 += __shfl_xor(acc0, 16, 64);
    acc0 += __shfl_xor(acc0, 32, 64);
#pragma unroll
    for (int m = 0; m < 3; ++m) {
        acc1[m] += __shfl_xor(acc1[m], 16, 64);
        acc1[m] += __shfl_xor(acc1[m], 32, 64);
    }
#pragma unroll
    for (int m = 0; m < 9; ++m) {
        acc2[m] += __shfl_xor(acc2[m], 16, 64);
        acc2[m] += __shfl_xor(acc2[m], 32, 64);
    }

    if (j == 0) {
        int t = node * NCH + k;
        out0[t] = acc0;
        float* o1p = out1 + (size_t)t * 3;
#pragma unroll
        for (int m = 0; m < 3; ++m) o1p[m] = acc1[m];
        float* o2p = out2 + (size_t)t * 9;
#pragma unroll
        for (int m = 0; m < 9; ++m) o2p[m] = acc2[m];
    }
}

extern "C" void kernel_launch(void* const* d_in, const int* in_sizes, int n_in,
                              void* d_out, int out_size, void* d_ws, size_t ws_size,
                              hipStream_t stream) {
    const float* h0  = (const float*)d_in[0];
    const float* h1  = (const float*)d_in[1];
    const float* h2  = (const float*)d_in[2];
    const float* pos = (const float*)d_in[3];
    // d_in[4] = channel_weights: dead in the reference dataflow
    const int* edge_index = (const int*)d_in[5];
    const int* src = edge_index;
    const int* dst = edge_index + N_EDGES;

    float* out = (float*)d_out;
    float* out0 = out;                                  // [N,16]
    float* out1 = out + (size_t)N_NODES * NCH;          // [N,16,3]
    float* out2 = out + (size_t)N_NODES * NCH * 4;      // [N,16,9]

    // workspace layout (16-B aligned first)
    float4* edata  = (float4*)d_ws;                      // [E]      6.4 MB
    float*  radial = (float*)(edata + N_EDGES);          // [E*16]  25.6 MB
    float*  dists  = radial + (size_t)N_EDGES * NCH;     // [E]      1.6 MB
    float*  unit   = dists + N_EDGES;                    // [E*3]    4.8 MB
    int* cnt       = (int*)(unit + (size_t)N_EDGES * 3); // [N]
    int* incl      = cnt + N_NODES;                      // [N]
    int* bsum      = incl + N_NODES;                     // [256]
    int* offsets   = bsum + 256;                         // [N+1]
    int* cursor    = offsets + N_NODES + 1;              // [N]
    // total ~39 MB

    const int NB_EDGES = (N_EDGES + 255) / 256;  // 1563
    const int NB_NODES = (N_NODES + 255) / 256;  // 196

    hipMemsetAsync(cnt, 0, N_NODES * sizeof(int), stream);
    geom_hist_kernel<<<NB_EDGES, 256, 0, stream>>>(pos, src, dst, dists, unit, cnt);
    scan_blocks_kernel<<<NB_NODES, 256, 0, stream>>>(cnt, incl, bsum);
    finalize_kernel<<<NB_NODES, 256, 0, stream>>>(cnt, incl, bsum, offsets, cursor);
    fill_kernel<<<NB_EDGES, 256, 0, stream>>>(src, dst, unit, dists, cursor, edata, radial);

    // one wave (64 threads) per node
    const int TOTAL = N_NODES * 64;
    node_wave_kernel<<<(TOTAL + 255) / 256, 256, 0, stream>>>(
        h0, h1, h2, offsets, edata, radial, out0, out1, out2);
}

// Round 5
// 203.757 us; speedup vs baseline: 1.5788x; 1.0364x over previous
//
#include <hip/hip_runtime.h>
#include <math.h>

#define N_NODES   50000
#define N_EDGES   400000
#define NCH       16
#define RCUT      10.0f

// ---------------- K1: per-edge distance + src histogram ----------------
__global__ void geom_hist_kernel(const float* __restrict__ pos,
                                 const int* __restrict__ src,
                                 const int* __restrict__ dst,
                                 float* __restrict__ dists,
                                 int* __restrict__ cnt) {
    int e = blockIdx.x * blockDim.x + threadIdx.x;
    if (e >= N_EDGES) return;
    int s = src[e];
    int d = dst[e];
    float rx = pos[3 * s + 0] - pos[3 * d + 0];
    float ry = pos[3 * s + 1] - pos[3 * d + 1];
    float rz = pos[3 * s + 2] - pos[3 * d + 2];
    dists[e] = sqrtf(rx * rx + ry * ry + rz * rz);
    atomicAdd(&cnt[s], 1);
}

// ---------------- K2: per-256-block inclusive scan ----------------
__global__ void scan_blocks_kernel(const int* __restrict__ cnt,
                                   int* __restrict__ incl,
                                   int* __restrict__ bsum) {
    __shared__ int sh[256];
    int t = threadIdx.x;
    int i = blockIdx.x * 256 + t;
    int v = (i < N_NODES) ? cnt[i] : 0;
    sh[t] = v;
    __syncthreads();
    for (int s = 1; s < 256; s <<= 1) {
        int x = 0;
        if (t >= s) x = sh[t - s];
        __syncthreads();
        if (t >= s) sh[t] += x;
        __syncthreads();
    }
    if (i < N_NODES) incl[i] = sh[t];
    if (t == 255) bsum[blockIdx.x] = sh[255];
}

// ---------------- K3: finalize offsets ----------------
__global__ void finalize_kernel(const int* __restrict__ cnt,
                                const int* __restrict__ incl,
                                const int* __restrict__ bsum,
                                int* __restrict__ offsets,
                                int* __restrict__ cursor) {
    __shared__ int sh[256];
    int t = threadIdx.x;
    int b = blockIdx.x;
    sh[t] = (t < b) ? bsum[t] : 0;
    __syncthreads();
    for (int s = 128; s > 0; s >>= 1) {
        if (t < s) sh[t] += sh[t + s];
        __syncthreads();
    }
    int base = sh[0];
    int i = b * 256 + t;
    if (i < N_NODES) {
        int off = incl[i] - cnt[i] + base;
        offsets[i] = off;
        cursor[i] = off;
    }
    if (b == 0 && t == 0) offsets[N_NODES] = N_EDGES;
}

// ---------------- K4: fill slot-ordered edata {u, dst} + csr {e} ----------------
__global__ void fill_kernel(const int* __restrict__ src,
                            const int* __restrict__ dst,
                            const float* __restrict__ pos,
                            int* __restrict__ cursor,
                            float4* __restrict__ edata,
                            int* __restrict__ csr) {
    int e = blockIdx.x * blockDim.x + threadIdx.x;
    if (e >= N_EDGES) return;
    int s = src[e];
    int d = dst[e];
    float rx = pos[3 * s + 0] - pos[3 * d + 0];
    float ry = pos[3 * s + 1] - pos[3 * d + 1];
    float rz = pos[3 * s + 2] - pos[3 * d + 2];
    float inv = 1.0f / sqrtf(rx * rx + ry * ry + rz * rz);
    int slot = atomicAdd(&cursor[s], 1);
    float4 ed;
    ed.x = rx * inv;
    ed.y = ry * inv;
    ed.z = rz * inv;
    ed.w = __int_as_float(d);
    edata[slot] = ed;
    csr[slot] = e;
}

// ---------------- K5: main — one WAVE per node, prefetch-pipelined ----------------
// lane = j*16 + k: k = channel, j = 4-way edge split; xor-shuffle reduce over j.
__global__ void node_wave_kernel(const float* __restrict__ h0,
                                 const float* __restrict__ h1,
                                 const float* __restrict__ h2,
                                 const int* __restrict__ offsets,
                                 const float4* __restrict__ edata,
                                 const int* __restrict__ csr,
                                 const float* __restrict__ dists,
                                 float* __restrict__ out0,
                                 float* __restrict__ out1,
                                 float* __restrict__ out2) {
    int gid = blockIdx.x * blockDim.x + threadIdx.x;
    int node = gid >> 6;
    if (node >= N_NODES) return;
    int lane = threadIdx.x & 63;
    int k = lane & 15;
    int j = lane >> 4;
    int beg = offsets[node];
    int end = offsets[node + 1];

    float acc0 = 0.0f;
    float acc1[3] = {0.0f, 0.0f, 0.0f};
    float acc2[9] = {0.0f, 0.0f, 0.0f, 0.0f, 0.0f, 0.0f, 0.0f, 0.0f, 0.0f};

    int i = beg + j;
    float4 ed;
    int e = 0;
    if (i < end) {
        ed = edata[i];
        e = csr[i];
    }
    while (i < end) {
        int inext = i + 4;
        float4 edn = ed;
        int en = e;
        if (inext < end) {          // prefetch next iteration (overlaps h-chain)
            edn = edata[inext];
            en = csr[inext];
        }

        int d = __float_as_int(ed.w);

        // radial (faithful [K,E]->[E,K] reshape): f = e*16+k
        unsigned f = (unsigned)e * NCH + (unsigned)k;
        unsigned n_idx = f / (unsigned)N_EDGES;       // magic-mul div
        unsigned e_idx = f - n_idx * (unsigned)N_EDGES;
        float r = dists[e_idx];                        // 16 consecutive floats / j-group
        float R = 0.44721359549995794f *
                  __sinf((float)(n_idx + 1) * 0.3141592653589793f * r) / r;

        float ux = ed.x, uy = ed.y, uz = ed.z;
        float u[3] = {ux, uy, uz};

        float A0 = h0[d * NCH + k];
        const float* a1p = h1 + ((size_t)d * NCH + k) * 3;
        float A1[3] = {a1p[0], a1p[1], a1p[2]};
        const float* a2p = h2 + ((size_t)d * NCH + k) * 9;
        float A2[9];
#pragma unroll
        for (int q2 = 0; q2 < 9; ++q2) A2[q2] = a2p[q2];

        float d1 = A1[0] * ux + A1[1] * uy + A1[2] * uz;   // A1.u
        float tA = A2[0] + A2[4] + A2[8];                   // tr(A2)
        float v0 = A2[0] * ux + A2[1] * uy + A2[2] * uz;    // A2 u
        float v1 = A2[3] * ux + A2[4] * uy + A2[5] * uz;
        float v2 = A2[6] * ux + A2[7] * uy + A2[8] * uz;
        float w0 = A2[0] * ux + A2[3] * uy + A2[6] * uz;    // A2^T u
        float w1 = A2[1] * ux + A2[4] * uy + A2[7] * uz;
        float w2 = A2[2] * ux + A2[5] * uy + A2[8] * uz;
        float q = ux * v0 + uy * v1 + uz * v2;              // u^T A2 u

        acc0 += R * (2.0f * A0 + d1 + 2.0f * tA + 2.0f * q);

        float svw[3] = {v0 + w0, v1 + w1, v2 + w2};
        float a0t = A0 + tA;
#pragma unroll
        for (int m = 0; m < 3; ++m) {
            acc1[m] += R * (A0 * u[m] + 2.0f * A1[m] + 2.0f * d1 * u[m]
                            + svw[m] + tA * u[m]);
#pragma unroll
            for (int nn = 0; nn < 3; ++nn) {
                acc2[3 * m + nn] += R * (a0t * u[m] * u[nn] + A1[m] * u[nn]
                                         + 2.0f * A2[3 * m + nn]
                                         + 2.0f * svw[m] * u[nn]);
            }
        }

        ed = edn;
        e = en;
        i = inext;
    }

    // reduce across j (lanes xor 16, xor 32)
    acc0 += __shfl_xor(acc0, 16, 64);
    acc0 += __shfl_xor(acc0, 32, 64);
#pragma unroll
    for (int m = 0; m < 3; ++m) {
        acc1[m] += __shfl_xor(acc1[m], 16, 64);
        acc1[m] += __shfl_xor(acc1[m], 32, 64);
    }
#pragma unroll
    for (int m = 0; m < 9; ++m) {
        acc2[m] += __shfl_xor(acc2[m], 16, 64);
        acc2[m] += __shfl_xor(acc2[m], 32, 64);
    }

    if (j == 0) {
        int t = node * NCH + k;
        out0[t] = acc0;
        float* o1p = out1 + (size_t)t * 3;
#pragma unroll
        for (int m = 0; m < 3; ++m) o1p[m] = acc1[m];
        float* o2p = out2 + (size_t)t * 9;
#pragma unroll
        for (int m = 0; m < 9; ++m) o2p[m] = acc2[m];
    }
}

extern "C" void kernel_launch(void* const* d_in, const int* in_sizes, int n_in,
                              void* d_out, int out_size, void* d_ws, size_t ws_size,
                              hipStream_t stream) {
    const float* h0  = (const float*)d_in[0];
    const float* h1  = (const float*)d_in[1];
    const float* h2  = (const float*)d_in[2];
    const float* pos = (const float*)d_in[3];
    // d_in[4] = channel_weights: dead in the reference dataflow
    const int* edge_index = (const int*)d_in[5];
    const int* src = edge_index;
    const int* dst = edge_index + N_EDGES;

    float* out = (float*)d_out;
    float* out0 = out;                                  // [N,16]
    float* out1 = out + (size_t)N_NODES * NCH;          // [N,16,3]
    float* out2 = out + (size_t)N_NODES * NCH * 4;      // [N,16,9]

    // workspace layout (16-B aligned first) — ~11 MB total
    float4* edata  = (float4*)d_ws;                      // [E]   6.4 MB
    float*  dists  = (float*)(edata + N_EDGES);          // [E]   1.6 MB
    int* csr       = (int*)(dists + N_EDGES);            // [E]   1.6 MB
    int* cnt       = csr + N_EDGES;                      // [N]
    int* incl      = cnt + N_NODES;                      // [N]
    int* bsum      = incl + N_NODES;                     // [256]
    int* offsets   = bsum + 256;                         // [N+1]
    int* cursor    = offsets + N_NODES + 1;              // [N]

    const int NB_EDGES = (N_EDGES + 255) / 256;  // 1563
    const int NB_NODES = (N_NODES + 255) / 256;  // 196

    hipMemsetAsync(cnt, 0, N_NODES * sizeof(int), stream);
    geom_hist_kernel<<<NB_EDGES, 256, 0, stream>>>(pos, src, dst, dists, cnt);
    scan_blocks_kernel<<<NB_NODES, 256, 0, stream>>>(cnt, incl, bsum);
    finalize_kernel<<<NB_NODES, 256, 0, stream>>>(cnt, incl, bsum, offsets, cursor);
    fill_kernel<<<NB_EDGES, 256, 0, stream>>>(src, dst, pos, cursor, edata, csr);

    // one wave (64 threads) per node
    const int TOTAL = N_NODES * 64;
    node_wave_kernel<<<(TOTAL + 255) / 256, 256, 0, stream>>>(
        h0, h1, h2, offsets, edata, csr, dists, out0, out1, out2);
}